// Round 4
// baseline (273.865 us; speedup 1.0000x reference)
//
#include <hip/hip_runtime.h>
#include <hip/hip_bf16.h>

typedef unsigned short u16;

// Problem constants
#define BB 4
#define TT 2048
#define DIM 512
#define NH 8
#define DH 64
#define DECAY 0.9f

// Retention chunking
#define CC 64
#define NC 32
#define BHN 32

// Scan chunking (fused lookback scan)
#define SCH 64
#define SNC 32

// GEMM tiling
#define TM 128
#define TN 128
#define BK 64

// retention LDS row stride (u16): 64 + 8 pad; rows stay 16B-aligned
#define SS 72

typedef __attribute__((ext_vector_type(8))) short bf16x8;
typedef __attribute__((ext_vector_type(4))) float f32x4;

__device__ __forceinline__ u16 f2bfu(float f) {
  union { float f; unsigned int u; } c; c.f = f;
  unsigned int u = c.u + 0x7FFFu + ((c.u >> 16) & 1u);  // RNE
  return (u16)(u >> 16);
}
__device__ __forceinline__ float bf2f(u16 u) {
  union { unsigned int u; float f; } c; c.u = ((unsigned int)u) << 16;
  return c.f;
}

__device__ __forceinline__ void gl_lds16(const void* g, void* l) {
  __builtin_amdgcn_global_load_lds(
      (const __attribute__((address_space(1))) void*)g,
      (__attribute__((address_space(3))) void*)(unsigned int)(unsigned long long)l,
      16, 0, 0);
}

// ---------------------------------------------------------------------------
// cvt: fp32 -> bf16 (4 elems/thread); block 0 also zeroes lookback flags
// ---------------------------------------------------------------------------
__global__ void cvt_bf16(const float* __restrict__ x, u16* __restrict__ y,
                         int* __restrict__ flags) {
  if (blockIdx.x == 0 && threadIdx.x < SNC * 8) flags[threadIdx.x] = 0;
  int i = blockIdx.x * 256 + threadIdx.x;
  float4 f = ((const float4*)x)[i];
  ushort4 u;
  u.x = f2bfu(f.x); u.y = f2bfu(f.y); u.z = f2bfu(f.z); u.w = f2bfu(f.w);
  ((ushort4*)y)[i] = u;
}

// ---------------------------------------------------------------------------
// weight transpose + convert: Wt[m][n][k] = bf16(W_m[k][n])
// ---------------------------------------------------------------------------
__global__ void wtrans(const float* __restrict__ W0, const float* __restrict__ W1,
                       const float* __restrict__ W2, const float* __restrict__ W3,
                       u16* __restrict__ Wt) {
  __shared__ float t[32][33];
  int m = blockIdx.z;
  const float* W = (m == 0) ? W0 : (m == 1) ? W1 : (m == 2) ? W2 : W3;
  int n0 = blockIdx.x * 32, k0 = blockIdx.y * 32;
  int tx = threadIdx.x & 31, ty = threadIdx.x >> 5;
#pragma unroll
  for (int r = 0; r < 32; r += 8)
    t[ty + r][tx] = W[(size_t)(k0 + ty + r) * DIM + n0 + tx];
  __syncthreads();
  u16* o = Wt + (size_t)m * DIM * DIM;
#pragma unroll
  for (int r = 0; r < 32; r += 8)
    o[(size_t)(n0 + ty + r) * DIM + k0 + tx] = f2bfu(t[tx][ty + r]);
}

// ---------------------------------------------------------------------------
// MFMA GEMM (m97 structure): C = act(A @ Bt^T + bias), 128x128 tile
// ---------------------------------------------------------------------------
__global__ __launch_bounds__(256) void gemm_bt(
    const u16* __restrict__ A, const u16* __restrict__ Bt,
    const float* __restrict__ b0, const float* __restrict__ b1,
    const float* __restrict__ b2,
    float* __restrict__ C0, float* __restrict__ C1, float* __restrict__ C2,
    int act_mask) {
  __shared__ __align__(16) u16 As[TM * BK];
  __shared__ __align__(16) u16 Bs[TN * BK];
  int tid = threadIdx.x;
  int wave = tid >> 6, lane = tid & 63;
  int nTile = blockIdx.x, mTile = blockIdx.y;
  int group = (nTile * TN) >> 9;
  const float* bias = (group == 0) ? b0 : (group == 1) ? b1 : b2;
  float* C = (group == 0) ? C0 : (group == 1) ? C1 : C2;
  int act = (act_mask >> group) & 1;

  int wm = (wave >> 1) * 64, wn = (wave & 1) * 64;
  int rowA = lane & 15, khalf = lane >> 4;

  f32x4 acc[4][4];
#pragma unroll
  for (int i = 0; i < 4; ++i)
#pragma unroll
    for (int j = 0; j < 4; ++j) acc[i][j] = (f32x4){0.f, 0.f, 0.f, 0.f};

  const u16* Abase = A + (size_t)mTile * TM * 512;
  const u16* Bbase = Bt + (size_t)nTile * TN * 512;

  for (int kk = 0; kk < 512; kk += BK) {
#pragma unroll
    for (int i = 0; i < 4; ++i) {
      int o = (wave * 4 + i) * 64 + lane;
      int row = o >> 3, gk = (o & 7) ^ (row & 7);
      gl_lds16(Abase + (size_t)row * 512 + kk + gk * 8, &As[o * 8]);
    }
#pragma unroll
    for (int i = 0; i < 4; ++i) {
      int o = (wave * 4 + i) * 64 + lane;
      int row = o >> 3, gk = (o & 7) ^ (row & 7);
      gl_lds16(Bbase + (size_t)row * 512 + kk + gk * 8, &Bs[o * 8]);
    }
    __syncthreads();
#pragma unroll
    for (int k0 = 0; k0 < 2; ++k0) {
      bf16x8 af[4], bfr[4];
#pragma unroll
      for (int mi = 0; mi < 4; ++mi) {
        int rr = wm + mi * 16 + rowA;
        int gk = k0 * 4 + khalf;
        int o = rr * 8 + (gk ^ (rr & 7));
        af[mi] = *(const bf16x8*)&As[o * 8];
      }
#pragma unroll
      for (int ni = 0; ni < 4; ++ni) {
        int rr = wn + ni * 16 + rowA;
        int gk = k0 * 4 + khalf;
        int o = rr * 8 + (gk ^ (rr & 7));
        bfr[ni] = *(const bf16x8*)&Bs[o * 8];
      }
#pragma unroll
      for (int mi = 0; mi < 4; ++mi)
#pragma unroll
        for (int ni = 0; ni < 4; ++ni)
          acc[mi][ni] = __builtin_amdgcn_mfma_f32_16x16x32_bf16(
              af[mi], bfr[ni], acc[mi][ni], 0, 0, 0);
    }
    __syncthreads();
  }
  int cloc = lane & 15, rq = (lane >> 4) * 4;
#pragma unroll
  for (int mi = 0; mi < 4; ++mi) {
#pragma unroll
    for (int r = 0; r < 4; ++r) {
      int m = mTile * TM + wm + mi * 16 + rq + r;
#pragma unroll
      for (int ni = 0; ni < 4; ++ni) {
        int n = (nTile * TN + wn + ni * 16 + cloc) & 511;
        float vv = acc[mi][ni][r] + bias[n];
        if (act) vv = 1.0f / (1.0f + __expf(-vv));
        C[(size_t)m * 512 + n] = vv;
      }
    }
  }
}

// ---------------------------------------------------------------------------
// Fused single-pass linear scan with decoupled lookback.
// h_t = a_t*h_{t-1} + b_t ; emits hg = bf16(h*g).
// Grid (8 channel-groups, SNC chunks), 256 threads, chunk tile in LDS
// (128 KB -> 1 block/CU, all 256 blocks co-resident -> no deadlock).
// ---------------------------------------------------------------------------
__global__ __launch_bounds__(256) void scan_fused(
    const float* __restrict__ a, const float* __restrict__ b,
    const float* __restrict__ g, u16* __restrict__ hg,
    float* __restrict__ PA, float* __restrict__ PB,
    float* __restrict__ IN, int* __restrict__ flags) {
  __shared__ float As[SCH][256];
  __shared__ float Bs[SCH][256];
  int grp = blockIdx.x, c = blockIdx.y;
  int tid = threadIdx.x;
  int ch = grp * 256 + tid;           // [0, 2048)
  int bb = ch >> 9, d = ch & 511;
  size_t base = ((size_t)bb * TT + c * SCH) * DIM + d;

  // phase A: local scan, tile into LDS
  float h = 0.f, pA = 1.f;
#pragma unroll 4
  for (int t = 0; t < SCH; ++t) {
    float av = a[base + (size_t)t * DIM];
    float bv = b[base + (size_t)t * DIM];
    As[t][tid] = av; Bs[t][tid] = bv;
    h = fmaf(av, h, bv);
    pA *= av;
  }
  int slot = c * 2048 + ch;
  __hip_atomic_store(&PA[slot], pA, __ATOMIC_RELAXED, __HIP_MEMORY_SCOPE_AGENT);
  __hip_atomic_store(&PB[slot], h, __ATOMIC_RELAXED, __HIP_MEMORY_SCOPE_AGENT);
  __syncthreads();
  if (tid == 0) {
    __threadfence();
    __hip_atomic_store(&flags[c * 8 + grp], 1, __ATOMIC_RELEASE,
                       __HIP_MEMORY_SCOPE_AGENT);
  }
  // lookback: compose transforms of chunks c-1 .. 0
  float fA = 1.f, fB = 0.f, carry = 0.f;
  bool done = (c == 0);
  for (int p = c - 1; p >= 0 && !done; --p) {
    int fl;
    while (!(fl = __hip_atomic_load(&flags[p * 8 + grp], __ATOMIC_ACQUIRE,
                                    __HIP_MEMORY_SCOPE_AGENT)))
      __builtin_amdgcn_s_sleep(1);
    int s2 = p * 2048 + ch;
    if (fl == 2) {
      float inc = __hip_atomic_load(&IN[s2], __ATOMIC_RELAXED, __HIP_MEMORY_SCOPE_AGENT);
      carry = fmaf(fA, inc, fB);
      done = true;
    } else {
      float a2 = __hip_atomic_load(&PA[s2], __ATOMIC_RELAXED, __HIP_MEMORY_SCOPE_AGENT);
      float b2 = __hip_atomic_load(&PB[s2], __ATOMIC_RELAXED, __HIP_MEMORY_SCOPE_AGENT);
      fB = fmaf(fA, b2, fB);
      fA *= a2;
    }
  }
  if (!done) carry = fB;
  // publish inclusive
  float incl = fmaf(pA, carry, h);
  __hip_atomic_store(&IN[slot], incl, __ATOMIC_RELAXED, __HIP_MEMORY_SCOPE_AGENT);
  __syncthreads();
  if (tid == 0) {
    __threadfence();
    __hip_atomic_store(&flags[c * 8 + grp], 2, __ATOMIC_RELEASE,
                       __HIP_MEMORY_SCOPE_AGENT);
  }
  // phase B: rescan from LDS with carry, gate, emit bf16
  float hh = carry;
  for (int t = 0; t < SCH; ++t) {
    size_t idx = base + (size_t)t * DIM;
    hh = fmaf(As[t][tid], hh, Bs[t][tid]);
    hg[idx] = f2bfu(hh * g[idx]);
  }
}

// ---------------------------------------------------------------------------
// Retention phase 1 (MFMA): per-chunk transposed state
// KVT[c][bh][e][d] = sum_j (V[j][e]) * (decay^{63-j} K[j][d])
// ---------------------------------------------------------------------------
__global__ __launch_bounds__(256) void ret_kv(const float* __restrict__ k,
                                              const float* __restrict__ v,
                                              float* __restrict__ KVT) {
  __shared__ __align__(16) u16 VT[64 * SS];
  __shared__ __align__(16) u16 KT[64 * SS];
  int bh = blockIdx.x, c = blockIdx.y;
  int b = bh >> 3, h = bh & 7;
  int tid = threadIdx.x;
  int wave = tid >> 6, lane = tid & 63;
  size_t base = ((size_t)(b * TT + c * CC)) * DIM + h * DH;
  int row = tid >> 2, part = tid & 3, e0 = part * 16;
  float w = __powf(DECAY, (float)(63 - row));
  {
    const float4* vs = (const float4*)(v + base + (size_t)row * DIM + e0);
    const float4* ks = (const float4*)(k + base + (size_t)row * DIM + e0);
#pragma unroll
    for (int u4 = 0; u4 < 4; ++u4) {
      float4 fv = vs[u4], fk = ks[u4];
      VT[(e0 + u4 * 4 + 0) * SS + row] = f2bfu(fv.x);
      VT[(e0 + u4 * 4 + 1) * SS + row] = f2bfu(fv.y);
      VT[(e0 + u4 * 4 + 2) * SS + row] = f2bfu(fv.z);
      VT[(e0 + u4 * 4 + 3) * SS + row] = f2bfu(fv.w);
      KT[(e0 + u4 * 4 + 0) * SS + row] = f2bfu(fk.x * w);
      KT[(e0 + u4 * 4 + 1) * SS + row] = f2bfu(fk.y * w);
      KT[(e0 + u4 * 4 + 2) * SS + row] = f2bfu(fk.z * w);
      KT[(e0 + u4 * 4 + 3) * SS + row] = f2bfu(fk.w * w);
    }
  }
  __syncthreads();
  int wm = (wave >> 1) * 32, wn = (wave & 1) * 32;
  int rowA = lane & 15, khalf = lane >> 4;
  f32x4 acc[2][2];
#pragma unroll
  for (int i = 0; i < 2; ++i)
#pragma unroll
    for (int j = 0; j < 2; ++j) acc[i][j] = (f32x4){0.f, 0.f, 0.f, 0.f};
#pragma unroll
  for (int k0 = 0; k0 < 2; ++k0) {
    int gk = k0 * 4 + khalf;
    bf16x8 af[2], bfr[2];
#pragma unroll
    for (int mi = 0; mi < 2; ++mi)
      af[mi] = *(const bf16x8*)&VT[(wm + mi * 16 + rowA) * SS + gk * 8];
#pragma unroll
    for (int ni = 0; ni < 2; ++ni)
      bfr[ni] = *(const bf16x8*)&KT[(wn + ni * 16 + rowA) * SS + gk * 8];
#pragma unroll
    for (int mi = 0; mi < 2; ++mi)
#pragma unroll
      for (int ni = 0; ni < 2; ++ni)
        acc[mi][ni] = __builtin_amdgcn_mfma_f32_16x16x32_bf16(
            af[mi], bfr[ni], acc[mi][ni], 0, 0, 0);
  }
  int cloc = lane & 15, rq = (lane >> 4) * 4;
  float* o = KVT + ((size_t)(c * BHN + bh)) * 4096;
#pragma unroll
  for (int mi = 0; mi < 2; ++mi)
#pragma unroll
    for (int r = 0; r < 4; ++r) {
      int e = wm + mi * 16 + rq + r;
#pragma unroll
      for (int ni = 0; ni < 2; ++ni) {
        int dd = wn + ni * 16 + cloc;
        o[e * 64 + dd] = acc[mi][ni][r];
      }
    }
}

// ---------------------------------------------------------------------------
// Retention phase 2: exclusive chunk scan; emits bf16 P^T[e][d] per chunk
// ---------------------------------------------------------------------------
__global__ void ret_scan(const float* __restrict__ KVT, u16* __restrict__ Ptb) {
  int gid = blockIdx.x * 256 + threadIdx.x;
  int bh = gid >> 12, ed = gid & 4095;
  float carry = 0.f;
  const float dC = __powf(DECAY, (float)CC);
  for (int c = 0; c < NC; ++c) {
    size_t idx = ((size_t)(c * BHN + bh)) * 4096 + ed;
    Ptb[idx] = f2bfu(carry);
    carry = fmaf(dC, carry, KVT[idx]);
  }
}

// ---------------------------------------------------------------------------
// Retention phase 3 (MFMA): S = QK^T, mask; O = [S~ | dQ] @ [V^T ; P^T]
// ---------------------------------------------------------------------------
__global__ __launch_bounds__(256) void ret_out(
    const u16* __restrict__ qbf, const float* __restrict__ kg,
    const float* __restrict__ vg, const u16* __restrict__ Ptb,
    float* __restrict__ out) {
  __shared__ __align__(16) u16 Qs[64 * SS];
  __shared__ __align__(16) u16 Ks[64 * SS];  // becomes V^T after S-phase
  __shared__ __align__(16) u16 Sa[64 * SS];
  __shared__ __align__(16) u16 Ps[64 * SS];
  __shared__ float dp[66];
  int bh = blockIdx.x, c = blockIdx.y;
  int b = bh >> 3, h = bh & 7;
  int tid = threadIdx.x;
  int wave = tid >> 6, lane = tid & 63;
  size_t base = ((size_t)(b * TT + c * CC)) * DIM + h * DH;
  if (tid < 66) dp[tid] = __powf(DECAY, (float)tid);
  int row = tid >> 2, part = tid & 3;
  // stage Q (bf16 direct), K (fp32 -> bf16)
  {
    const u16* qrow = qbf + base + (size_t)row * DIM + part * 16;
    *(uint4*)&Qs[row * SS + part * 16] = *(const uint4*)qrow;
    *(uint4*)&Qs[row * SS + part * 16 + 8] = *(const uint4*)(qrow + 8);
    const float4* ks = (const float4*)(kg + base + (size_t)row * DIM + part * 16);
    u16 tk[16];
#pragma unroll
    for (int u4 = 0; u4 < 4; ++u4) {
      float4 fk = ks[u4];
      tk[u4 * 4 + 0] = f2bfu(fk.x); tk[u4 * 4 + 1] = f2bfu(fk.y);
      tk[u4 * 4 + 2] = f2bfu(fk.z); tk[u4 * 4 + 3] = f2bfu(fk.w);
    }
    *(uint4*)&Ks[row * SS + part * 16] = *(uint4*)&tk[0];
    *(uint4*)&Ks[row * SS + part * 16 + 8] = *(uint4*)&tk[8];
  }
  __syncthreads();

  int wm = (wave >> 1) * 32, wn = (wave & 1) * 32;
  int rowA = lane & 15, khalf = lane >> 4;

  // --- S = Q K^T ---
  f32x4 accS[2][2];
#pragma unroll
  for (int i = 0; i < 2; ++i)
#pragma unroll
    for (int j = 0; j < 2; ++j) accS[i][j] = (f32x4){0.f, 0.f, 0.f, 0.f};
#pragma unroll
  for (int k0 = 0; k0 < 2; ++k0) {
    int g = k0 * 4 + khalf;
    bf16x8 af[2], bfv[2];
#pragma unroll
    for (int mi = 0; mi < 2; ++mi)
      af[mi] = *(const bf16x8*)&Qs[(wm + mi * 16 + rowA) * SS + g * 8];
#pragma unroll
    for (int ni = 0; ni < 2; ++ni)
      bfv[ni] = *(const bf16x8*)&Ks[(wn + ni * 16 + rowA) * SS + g * 8];
#pragma unroll
    for (int mi = 0; mi < 2; ++mi)
#pragma unroll
      for (int ni = 0; ni < 2; ++ni)
        accS[mi][ni] = __builtin_amdgcn_mfma_f32_16x16x32_bf16(
            af[mi], bfv[ni], accS[mi][ni], 0, 0, 0);
  }
  __syncthreads();

  // --- masked S -> Sa (bf16, A-layout) ---
  int cloc = lane & 15, rq = (lane >> 4) * 4;
#pragma unroll
  for (int mi = 0; mi < 2; ++mi)
#pragma unroll
    for (int ni = 0; ni < 2; ++ni)
#pragma unroll
      for (int r = 0; r < 4; ++r) {
        int i = wm + mi * 16 + rq + r;
        int j = wn + ni * 16 + cloc;
        float sv = (j <= i) ? accS[mi][ni][r] * dp[i - j] : 0.f;
        Sa[i * SS + j] = f2bfu(sv);
      }
  // --- Q <- decay^{i+1} * Q (in place) ---
  {
    u16* qp = &Qs[row * SS + part * 16];
    float s = dp[row + 1];
#pragma unroll
    for (int u = 0; u < 16; ++u) qp[u] = f2bfu(bf2f(qp[u]) * s);
  }
  // --- V^T into Ks region ---
  {
    int j = row, e0 = part * 16;
    const float4* vs = (const float4*)(vg + base + (size_t)j * DIM + e0);
#pragma unroll
    for (int u4 = 0; u4 < 4; ++u4) {
      float4 fv = vs[u4];
      Ks[(e0 + u4 * 4 + 0) * SS + j] = f2bfu(fv.x);
      Ks[(e0 + u4 * 4 + 1) * SS + j] = f2bfu(fv.y);
      Ks[(e0 + u4 * 4 + 2) * SS + j] = f2bfu(fv.z);
      Ks[(e0 + u4 * 4 + 3) * SS + j] = f2bfu(fv.w);
    }
  }
  // --- P^T tile ---
  {
    const u16* Pg = Ptb + ((size_t)(c * BHN + bh)) * 4096;
    *(uint4*)&Ps[row * SS + part * 16] = *(const uint4*)&Pg[row * 64 + part * 16];
    *(uint4*)&Ps[row * SS + part * 16 + 8] = *(const uint4*)&Pg[row * 64 + part * 16 + 8];
  }
  __syncthreads();

  // --- O = [S~ | Q] @ [V^T ; P^T], K = 128 ---
  f32x4 accO[2][2];
#pragma unroll
  for (int i = 0; i < 2; ++i)
#pragma unroll
    for (int j = 0; j < 2; ++j) accO[i][j] = (f32x4){0.f, 0.f, 0.f, 0.f};
#pragma unroll
  for (int k0 = 0; k0 < 4; ++k0) {
    bf16x8 af[2], bfv[2];
#pragma unroll
    for (int mi = 0; mi < 2; ++mi) {
      int rr = wm + mi * 16 + rowA;
      if (k0 < 2)
        af[mi] = *(const bf16x8*)&Sa[rr * SS + (k0 * 4 + khalf) * 8];
      else
        af[mi] = *(const bf16x8*)&Qs[rr * SS + ((k0 - 2) * 4 + khalf) * 8];
    }
#pragma unroll
    for (int ni = 0; ni < 2; ++ni) {
      int rr = wn + ni * 16 + rowA;
      if (k0 < 2)
        bfv[ni] = *(const bf16x8*)&Ks[rr * SS + (k0 * 4 + khalf) * 8];
      else
        bfv[ni] = *(const bf16x8*)&Ps[rr * SS + ((k0 - 2) * 4 + khalf) * 8];
    }
#pragma unroll
    for (int mi = 0; mi < 2; ++mi)
#pragma unroll
      for (int ni = 0; ni < 2; ++ni)
        accO[mi][ni] = __builtin_amdgcn_mfma_f32_16x16x32_bf16(
            af[mi], bfv[ni], accO[mi][ni], 0, 0, 0);
  }
  // --- epilogue: out += O ---
#pragma unroll
  for (int mi = 0; mi < 2; ++mi)
#pragma unroll
    for (int r = 0; r < 4; ++r) {
      int i = wm + mi * 16 + rq + r;
#pragma unroll
      for (int ni = 0; ni < 2; ++ni) {
        int e = wn + ni * 16 + cloc;
        float* op = &out[base + (size_t)i * DIM + e];
        *op += accO[mi][ni][r];
      }
    }
}

// ---------------------------------------------------------------------------
extern "C" void kernel_launch(void* const* d_in, const int* in_sizes, int n_in,
                              void* d_out, int out_size, void* d_ws, size_t ws_size,
                              hipStream_t stream) {
  const float* q  = (const float*)d_in[0];
  const float* k  = (const float*)d_in[1];
  const float* v  = (const float*)d_in[2];
  const float* Wa = (const float*)d_in[3];
  const float* ba = (const float*)d_in[4];
  const float* Wb = (const float*)d_in[5];
  const float* bb = (const float*)d_in[6];
  const float* Wg = (const float*)d_in[7];
  const float* bg = (const float*)d_in[8];
  const float* Wo = (const float*)d_in[9];
  const float* bo = (const float*)d_in[10];
  float* out = (float*)d_out;
  float* ws = (float*)d_ws;

  const size_t NEL = (size_t)BB * TT * DIM;  // 4,194,304
  float* Abuf = ws;                          // a; KVT aliases after scan_fused
  float* Bbuf = ws + NEL;                    // b
  float* Gbuf = ws + 2 * NEL;                // g; Ptb aliases after scan_fused
  u16* qbf    = (u16*)(ws + 3 * NEL);        // bf16 q (persists to ret_out)
  u16* hgbf   = (u16*)(ws + 3 * NEL + NEL / 2);
  u16* WtAll  = (u16*)(ws + 3 * NEL + NEL);
  float* sPA  = ws + 3 * NEL + NEL + 524288;  // SNC*2048 each
  float* sPB  = sPA + SNC * 2048;
  float* sIN  = sPB + SNC * 2048;
  int* flags  = (int*)(sIN + SNC * 2048);     // SNC*8 ints
  float* KVT  = Abuf;
  u16* Ptb    = (u16*)Gbuf;

  cvt_bf16<<<(int)(NEL / 4 / 256), 256, 0, stream>>>(q, qbf, flags);
  wtrans<<<dim3(16, 16, 4), 256, 0, stream>>>(Wa, Wb, Wg, Wo, WtAll);

  // fused q @ {Wa|Wb|Wg}: N = 1536, sigmoid on groups 0 and 2
  gemm_bt<<<dim3(12, 64), 256, 0, stream>>>(qbf, WtAll, ba, bb, bg,
                                            Abuf, Bbuf, Gbuf, 0b101);

  scan_fused<<<dim3(8, SNC), 256, 0, stream>>>(Abuf, Bbuf, Gbuf, hgbf,
                                               sPA, sPB, sIN, flags);

  // m_out = (h*g) @ Wo + bo -> out
  gemm_bt<<<dim3(4, 64), 256, 0, stream>>>(hgbf, WtAll + 3 * DIM * DIM,
                                           bo, bo, bo, out, out, out, 0);

  ret_kv<<<dim3(BHN, NC), 256, 0, stream>>>(k, v, KVT);
  ret_scan<<<(BHN * 4096) / 256, 256, 0, stream>>>(KVT, Ptb);
  ret_out<<<dim3(BHN, NC), 256, 0, stream>>>(qbf, k, v, Ptb, out);
}

// Round 5
// 210.562 us; speedup vs baseline: 1.3006x; 1.3006x over previous
//
#include <hip/hip_runtime.h>
#include <hip/hip_bf16.h>

typedef unsigned short u16;

// Problem constants
#define BB 4
#define TT 2048
#define DIM 512
#define NH 8
#define DH 64
#define DECAY 0.9f

// Retention chunking
#define CC 64
#define NC 32
#define BHN 32

// Scan chunking: CHS=32 -> 512 blocks -> 8 waves/CU (latency hiding; the
// R3 fused-lookback kernel at 1 block/CU was latency-bound at 97 us)
#define CHS 32
#define NSC 64

// GEMM tiling
#define TM 128
#define TN 128
#define BK 64

// retention LDS row stride (u16): 64 + 8 pad; rows stay 16B-aligned
#define SS 72

typedef __attribute__((ext_vector_type(8))) short bf16x8;
typedef __attribute__((ext_vector_type(4))) float f32x4;

__device__ __forceinline__ u16 f2bfu(float f) {
  union { float f; unsigned int u; } c; c.f = f;
  unsigned int u = c.u + 0x7FFFu + ((c.u >> 16) & 1u);  // RNE
  return (u16)(u >> 16);
}
__device__ __forceinline__ float bf2f(u16 u) {
  union { unsigned int u; float f; } c; c.u = ((unsigned int)u) << 16;
  return c.f;
}

__device__ __forceinline__ void gl_lds16(const void* g, void* l) {
  __builtin_amdgcn_global_load_lds(
      (const __attribute__((address_space(1))) void*)g,
      (__attribute__((address_space(3))) void*)(unsigned int)(unsigned long long)l,
      16, 0, 0);
}

// ---------------------------------------------------------------------------
// cvt: fp32 -> bf16 (4 elems/thread)
// ---------------------------------------------------------------------------
__global__ void cvt_bf16(const float* __restrict__ x, u16* __restrict__ y) {
  int i = blockIdx.x * 256 + threadIdx.x;
  float4 f = ((const float4*)x)[i];
  ushort4 u;
  u.x = f2bfu(f.x); u.y = f2bfu(f.y); u.z = f2bfu(f.z); u.w = f2bfu(f.w);
  ((ushort4*)y)[i] = u;
}

// ---------------------------------------------------------------------------
// weight transpose + convert: Wt[m][n][k] = bf16(W_m[k][n])
// ---------------------------------------------------------------------------
__global__ void wtrans(const float* __restrict__ W0, const float* __restrict__ W1,
                       const float* __restrict__ W2, const float* __restrict__ W3,
                       u16* __restrict__ Wt) {
  __shared__ float t[32][33];
  int m = blockIdx.z;
  const float* W = (m == 0) ? W0 : (m == 1) ? W1 : (m == 2) ? W2 : W3;
  int n0 = blockIdx.x * 32, k0 = blockIdx.y * 32;
  int tx = threadIdx.x & 31, ty = threadIdx.x >> 5;
#pragma unroll
  for (int r = 0; r < 32; r += 8)
    t[ty + r][tx] = W[(size_t)(k0 + ty + r) * DIM + n0 + tx];
  __syncthreads();
  u16* o = Wt + (size_t)m * DIM * DIM;
#pragma unroll
  for (int r = 0; r < 32; r += 8)
    o[(size_t)(n0 + ty + r) * DIM + k0 + tx] = f2bfu(t[tx][ty + r]);
}

// ---------------------------------------------------------------------------
// MFMA GEMM (m97 structure): C = act(A @ Bt^T + bias), 128x128 tile
// ---------------------------------------------------------------------------
__global__ __launch_bounds__(256) void gemm_bt(
    const u16* __restrict__ A, const u16* __restrict__ Bt,
    const float* __restrict__ b0, const float* __restrict__ b1,
    const float* __restrict__ b2,
    float* __restrict__ C0, float* __restrict__ C1, float* __restrict__ C2,
    int act_mask) {
  __shared__ __align__(16) u16 As[TM * BK];
  __shared__ __align__(16) u16 Bs[TN * BK];
  int tid = threadIdx.x;
  int wave = tid >> 6, lane = tid & 63;
  int nTile = blockIdx.x, mTile = blockIdx.y;
  int group = (nTile * TN) >> 9;
  const float* bias = (group == 0) ? b0 : (group == 1) ? b1 : b2;
  float* C = (group == 0) ? C0 : (group == 1) ? C1 : C2;
  int act = (act_mask >> group) & 1;

  int wm = (wave >> 1) * 64, wn = (wave & 1) * 64;
  int rowA = lane & 15, khalf = lane >> 4;

  f32x4 acc[4][4];
#pragma unroll
  for (int i = 0; i < 4; ++i)
#pragma unroll
    for (int j = 0; j < 4; ++j) acc[i][j] = (f32x4){0.f, 0.f, 0.f, 0.f};

  const u16* Abase = A + (size_t)mTile * TM * 512;
  const u16* Bbase = Bt + (size_t)nTile * TN * 512;

  for (int kk = 0; kk < 512; kk += BK) {
#pragma unroll
    for (int i = 0; i < 4; ++i) {
      int o = (wave * 4 + i) * 64 + lane;
      int row = o >> 3, gk = (o & 7) ^ (row & 7);
      gl_lds16(Abase + (size_t)row * 512 + kk + gk * 8, &As[o * 8]);
    }
#pragma unroll
    for (int i = 0; i < 4; ++i) {
      int o = (wave * 4 + i) * 64 + lane;
      int row = o >> 3, gk = (o & 7) ^ (row & 7);
      gl_lds16(Bbase + (size_t)row * 512 + kk + gk * 8, &Bs[o * 8]);
    }
    __syncthreads();
#pragma unroll
    for (int k0 = 0; k0 < 2; ++k0) {
      bf16x8 af[4], bfr[4];
#pragma unroll
      for (int mi = 0; mi < 4; ++mi) {
        int rr = wm + mi * 16 + rowA;
        int gk = k0 * 4 + khalf;
        int o = rr * 8 + (gk ^ (rr & 7));
        af[mi] = *(const bf16x8*)&As[o * 8];
      }
#pragma unroll
      for (int ni = 0; ni < 4; ++ni) {
        int rr = wn + ni * 16 + rowA;
        int gk = k0 * 4 + khalf;
        int o = rr * 8 + (gk ^ (rr & 7));
        bfr[ni] = *(const bf16x8*)&Bs[o * 8];
      }
#pragma unroll
      for (int mi = 0; mi < 4; ++mi)
#pragma unroll
        for (int ni = 0; ni < 4; ++ni)
          acc[mi][ni] = __builtin_amdgcn_mfma_f32_16x16x32_bf16(
              af[mi], bfr[ni], acc[mi][ni], 0, 0, 0);
    }
    __syncthreads();
  }
  int cloc = lane & 15, rq = (lane >> 4) * 4;
#pragma unroll
  for (int mi = 0; mi < 4; ++mi) {
#pragma unroll
    for (int r = 0; r < 4; ++r) {
      int m = mTile * TM + wm + mi * 16 + rq + r;
#pragma unroll
      for (int ni = 0; ni < 4; ++ni) {
        int n = (nTile * TN + wn + ni * 16 + cloc) & 511;
        float vv = acc[mi][ni][r] + bias[n];
        if (act) vv = 1.0f / (1.0f + __expf(-vv));
        C[(size_t)m * 512 + n] = vv;
      }
    }
  }
}

// ---------------------------------------------------------------------------
// 3-phase chunk-parallel linear scan, CHS=32 (512 blocks -> 8 waves/CU)
// ---------------------------------------------------------------------------
__global__ void scan_part(const float* __restrict__ a, const float* __restrict__ b,
                          float* __restrict__ SA, float* __restrict__ SB) {
  int ci = blockIdx.x;
  int ch = blockIdx.y * 256 + threadIdx.x;
  int bb = ch >> 9, d = ch & 511;
  size_t base = ((size_t)bb * TT + ci * CHS) * DIM + d;
  float h = 0.f, pA = 1.f;
#pragma unroll
  for (int t = 0; t < CHS; ++t) {
    float av = a[base + (size_t)t * DIM];
    float bv = b[base + (size_t)t * DIM];
    h = fmaf(av, h, bv);
    pA *= av;
  }
  SA[ci * 2048 + ch] = pA;
  SB[ci * 2048 + ch] = h;
}

__global__ void scan_carry(const float* __restrict__ SA, const float* __restrict__ SB,
                           float* __restrict__ CY) {
  int ch = blockIdx.x * 256 + threadIdx.x;
  float carry = 0.f;
#pragma unroll 8
  for (int ci = 0; ci < NSC; ++ci) {
    CY[ci * 2048 + ch] = carry;
    carry = fmaf(SA[ci * 2048 + ch], carry, SB[ci * 2048 + ch]);
  }
}

// apply + gate + bf16 convert fused: hg = bf16(h * g)
__global__ void scan_apply(const float* __restrict__ a, const float* __restrict__ b,
                           const float* __restrict__ g, const float* __restrict__ CY,
                           u16* __restrict__ hg) {
  int ci = blockIdx.x;
  int ch = blockIdx.y * 256 + threadIdx.x;
  int bb = ch >> 9, d = ch & 511;
  size_t base = ((size_t)bb * TT + ci * CHS) * DIM + d;
  float h = CY[ci * 2048 + ch];
#pragma unroll
  for (int t = 0; t < CHS; ++t) {
    size_t idx = base + (size_t)t * DIM;
    h = fmaf(a[idx], h, b[idx]);
    hg[idx] = f2bfu(h * g[idx]);
  }
}

// ---------------------------------------------------------------------------
// Retention phase 1 (MFMA): per-chunk transposed state
// KVT[c][bh][e][d] = sum_j (V[j][e]) * (decay^{63-j} K[j][d])
// ---------------------------------------------------------------------------
__global__ __launch_bounds__(256) void ret_kv(const float* __restrict__ k,
                                              const float* __restrict__ v,
                                              float* __restrict__ KVT) {
  __shared__ __align__(16) u16 VT[64 * SS];
  __shared__ __align__(16) u16 KT[64 * SS];
  int bh = blockIdx.x, c = blockIdx.y;
  int b = bh >> 3, h = bh & 7;
  int tid = threadIdx.x;
  int wave = tid >> 6, lane = tid & 63;
  size_t base = ((size_t)(b * TT + c * CC)) * DIM + h * DH;
  int row = tid >> 2, part = tid & 3, e0 = part * 16;
  float w = __powf(DECAY, (float)(63 - row));
  {
    const float4* vs = (const float4*)(v + base + (size_t)row * DIM + e0);
    const float4* ks = (const float4*)(k + base + (size_t)row * DIM + e0);
#pragma unroll
    for (int u4 = 0; u4 < 4; ++u4) {
      float4 fv = vs[u4], fk = ks[u4];
      VT[(e0 + u4 * 4 + 0) * SS + row] = f2bfu(fv.x);
      VT[(e0 + u4 * 4 + 1) * SS + row] = f2bfu(fv.y);
      VT[(e0 + u4 * 4 + 2) * SS + row] = f2bfu(fv.z);
      VT[(e0 + u4 * 4 + 3) * SS + row] = f2bfu(fv.w);
      KT[(e0 + u4 * 4 + 0) * SS + row] = f2bfu(fk.x * w);
      KT[(e0 + u4 * 4 + 1) * SS + row] = f2bfu(fk.y * w);
      KT[(e0 + u4 * 4 + 2) * SS + row] = f2bfu(fk.z * w);
      KT[(e0 + u4 * 4 + 3) * SS + row] = f2bfu(fk.w * w);
    }
  }
  __syncthreads();
  int wm = (wave >> 1) * 32, wn = (wave & 1) * 32;
  int rowA = lane & 15, khalf = lane >> 4;
  f32x4 acc[2][2];
#pragma unroll
  for (int i = 0; i < 2; ++i)
#pragma unroll
    for (int j = 0; j < 2; ++j) acc[i][j] = (f32x4){0.f, 0.f, 0.f, 0.f};
#pragma unroll
  for (int k0 = 0; k0 < 2; ++k0) {
    int gk = k0 * 4 + khalf;
    bf16x8 af[2], bfr[2];
#pragma unroll
    for (int mi = 0; mi < 2; ++mi)
      af[mi] = *(const bf16x8*)&VT[(wm + mi * 16 + rowA) * SS + gk * 8];
#pragma unroll
    for (int ni = 0; ni < 2; ++ni)
      bfr[ni] = *(const bf16x8*)&KT[(wn + ni * 16 + rowA) * SS + gk * 8];
#pragma unroll
    for (int mi = 0; mi < 2; ++mi)
#pragma unroll
      for (int ni = 0; ni < 2; ++ni)
        acc[mi][ni] = __builtin_amdgcn_mfma_f32_16x16x32_bf16(
            af[mi], bfr[ni], acc[mi][ni], 0, 0, 0);
  }
  int cloc = lane & 15, rq = (lane >> 4) * 4;
  float* o = KVT + ((size_t)(c * BHN + bh)) * 4096;
#pragma unroll
  for (int mi = 0; mi < 2; ++mi)
#pragma unroll
    for (int r = 0; r < 4; ++r) {
      int e = wm + mi * 16 + rq + r;
#pragma unroll
      for (int ni = 0; ni < 2; ++ni) {
        int dd = wn + ni * 16 + cloc;
        o[e * 64 + dd] = acc[mi][ni][r];
      }
    }
}

// ---------------------------------------------------------------------------
// Retention phase 2: exclusive chunk scan; emits bf16 P^T[e][d] per chunk
// ---------------------------------------------------------------------------
__global__ void ret_scan(const float* __restrict__ KVT, u16* __restrict__ Ptb) {
  int gid = blockIdx.x * 256 + threadIdx.x;
  int bh = gid >> 12, ed = gid & 4095;
  float carry = 0.f;
  const float dC = __powf(DECAY, (float)CC);
  for (int c = 0; c < NC; ++c) {
    size_t idx = ((size_t)(c * BHN + bh)) * 4096 + ed;
    Ptb[idx] = f2bfu(carry);
    carry = fmaf(dC, carry, KVT[idx]);
  }
}

// ---------------------------------------------------------------------------
// Retention phase 3 (MFMA): S = QK^T, mask; O = [S~ | dQ] @ [V^T ; P^T]
// ---------------------------------------------------------------------------
__global__ __launch_bounds__(256) void ret_out(
    const u16* __restrict__ qbf, const float* __restrict__ kg,
    const float* __restrict__ vg, const u16* __restrict__ Ptb,
    float* __restrict__ out) {
  __shared__ __align__(16) u16 Qs[64 * SS];
  __shared__ __align__(16) u16 Ks[64 * SS];  // becomes V^T after S-phase
  __shared__ __align__(16) u16 Sa[64 * SS];
  __shared__ __align__(16) u16 Ps[64 * SS];
  __shared__ float dp[66];
  int bh = blockIdx.x, c = blockIdx.y;
  int b = bh >> 3, h = bh & 7;
  int tid = threadIdx.x;
  int wave = tid >> 6, lane = tid & 63;
  size_t base = ((size_t)(b * TT + c * CC)) * DIM + h * DH;
  if (tid < 66) dp[tid] = __powf(DECAY, (float)tid);
  int row = tid >> 2, part = tid & 3;
  {
    const u16* qrow = qbf + base + (size_t)row * DIM + part * 16;
    *(uint4*)&Qs[row * SS + part * 16] = *(const uint4*)qrow;
    *(uint4*)&Qs[row * SS + part * 16 + 8] = *(const uint4*)(qrow + 8);
    const float4* ks = (const float4*)(kg + base + (size_t)row * DIM + part * 16);
    u16 tk[16];
#pragma unroll
    for (int u4 = 0; u4 < 4; ++u4) {
      float4 fk = ks[u4];
      tk[u4 * 4 + 0] = f2bfu(fk.x); tk[u4 * 4 + 1] = f2bfu(fk.y);
      tk[u4 * 4 + 2] = f2bfu(fk.z); tk[u4 * 4 + 3] = f2bfu(fk.w);
    }
    *(uint4*)&Ks[row * SS + part * 16] = *(uint4*)&tk[0];
    *(uint4*)&Ks[row * SS + part * 16 + 8] = *(uint4*)&tk[8];
  }
  __syncthreads();

  int wm = (wave >> 1) * 32, wn = (wave & 1) * 32;
  int rowA = lane & 15, khalf = lane >> 4;

  f32x4 accS[2][2];
#pragma unroll
  for (int i = 0; i < 2; ++i)
#pragma unroll
    for (int j = 0; j < 2; ++j) accS[i][j] = (f32x4){0.f, 0.f, 0.f, 0.f};
#pragma unroll
  for (int k0 = 0; k0 < 2; ++k0) {
    int g = k0 * 4 + khalf;
    bf16x8 af[2], bfv[2];
#pragma unroll
    for (int mi = 0; mi < 2; ++mi)
      af[mi] = *(const bf16x8*)&Qs[(wm + mi * 16 + rowA) * SS + g * 8];
#pragma unroll
    for (int ni = 0; ni < 2; ++ni)
      bfv[ni] = *(const bf16x8*)&Ks[(wn + ni * 16 + rowA) * SS + g * 8];
#pragma unroll
    for (int mi = 0; mi < 2; ++mi)
#pragma unroll
      for (int ni = 0; ni < 2; ++ni)
        accS[mi][ni] = __builtin_amdgcn_mfma_f32_16x16x32_bf16(
            af[mi], bfv[ni], accS[mi][ni], 0, 0, 0);
  }
  __syncthreads();

  int cloc = lane & 15, rq = (lane >> 4) * 4;
#pragma unroll
  for (int mi = 0; mi < 2; ++mi)
#pragma unroll
    for (int ni = 0; ni < 2; ++ni)
#pragma unroll
      for (int r = 0; r < 4; ++r) {
        int i = wm + mi * 16 + rq + r;
        int j = wn + ni * 16 + cloc;
        float sv = (j <= i) ? accS[mi][ni][r] * dp[i - j] : 0.f;
        Sa[i * SS + j] = f2bfu(sv);
      }
  {
    u16* qp = &Qs[row * SS + part * 16];
    float s = dp[row + 1];
#pragma unroll
    for (int u = 0; u < 16; ++u) qp[u] = f2bfu(bf2f(qp[u]) * s);
  }
  {
    int j = row, e0 = part * 16;
    const float4* vs = (const float4*)(vg + base + (size_t)j * DIM + e0);
#pragma unroll
    for (int u4 = 0; u4 < 4; ++u4) {
      float4 fv = vs[u4];
      Ks[(e0 + u4 * 4 + 0) * SS + j] = f2bfu(fv.x);
      Ks[(e0 + u4 * 4 + 1) * SS + j] = f2bfu(fv.y);
      Ks[(e0 + u4 * 4 + 2) * SS + j] = f2bfu(fv.z);
      Ks[(e0 + u4 * 4 + 3) * SS + j] = f2bfu(fv.w);
    }
  }
  {
    const u16* Pg = Ptb + ((size_t)(c * BHN + bh)) * 4096;
    *(uint4*)&Ps[row * SS + part * 16] = *(const uint4*)&Pg[row * 64 + part * 16];
    *(uint4*)&Ps[row * SS + part * 16 + 8] = *(const uint4*)&Pg[row * 64 + part * 16 + 8];
  }
  __syncthreads();

  f32x4 accO[2][2];
#pragma unroll
  for (int i = 0; i < 2; ++i)
#pragma unroll
    for (int j = 0; j < 2; ++j) accO[i][j] = (f32x4){0.f, 0.f, 0.f, 0.f};
#pragma unroll
  for (int k0 = 0; k0 < 4; ++k0) {
    bf16x8 af[2], bfv[2];
#pragma unroll
    for (int mi = 0; mi < 2; ++mi) {
      int rr = wm + mi * 16 + rowA;
      if (k0 < 2)
        af[mi] = *(const bf16x8*)&Sa[rr * SS + (k0 * 4 + khalf) * 8];
      else
        af[mi] = *(const bf16x8*)&Qs[rr * SS + ((k0 - 2) * 4 + khalf) * 8];
    }
#pragma unroll
    for (int ni = 0; ni < 2; ++ni) {
      int rr = wn + ni * 16 + rowA;
      if (k0 < 2)
        bfv[ni] = *(const bf16x8*)&Ks[rr * SS + (k0 * 4 + khalf) * 8];
      else
        bfv[ni] = *(const bf16x8*)&Ps[rr * SS + ((k0 - 2) * 4 + khalf) * 8];
    }
#pragma unroll
    for (int mi = 0; mi < 2; ++mi)
#pragma unroll
      for (int ni = 0; ni < 2; ++ni)
        accO[mi][ni] = __builtin_amdgcn_mfma_f32_16x16x32_bf16(
            af[mi], bfv[ni], accO[mi][ni], 0, 0, 0);
  }
#pragma unroll
  for (int mi = 0; mi < 2; ++mi)
#pragma unroll
    for (int r = 0; r < 4; ++r) {
      int i = wm + mi * 16 + rq + r;
#pragma unroll
      for (int ni = 0; ni < 2; ++ni) {
        int e = wn + ni * 16 + cloc;
        float* op = &out[base + (size_t)i * DIM + e];
        *op += accO[mi][ni][r];
      }
    }
}

// ---------------------------------------------------------------------------
extern "C" void kernel_launch(void* const* d_in, const int* in_sizes, int n_in,
                              void* d_out, int out_size, void* d_ws, size_t ws_size,
                              hipStream_t stream) {
  const float* q  = (const float*)d_in[0];
  const float* k  = (const float*)d_in[1];
  const float* v  = (const float*)d_in[2];
  const float* Wa = (const float*)d_in[3];
  const float* ba = (const float*)d_in[4];
  const float* Wb = (const float*)d_in[5];
  const float* bb = (const float*)d_in[6];
  const float* Wg = (const float*)d_in[7];
  const float* bg = (const float*)d_in[8];
  const float* Wo = (const float*)d_in[9];
  const float* bo = (const float*)d_in[10];
  float* out = (float*)d_out;
  float* ws = (float*)d_ws;

  const size_t NEL = (size_t)BB * TT * DIM;  // 4,194,304
  float* Abuf = ws;                          // a; KVT aliases after scan
  float* Bbuf = ws + NEL;                    // b
  float* Gbuf = ws + 2 * NEL;                // g; Ptb aliases after scan
  u16* qbf    = (u16*)(ws + 3 * NEL);        // bf16 q (persists to ret_out)
  u16* hgbf   = (u16*)(ws + 3 * NEL + NEL / 2);
  u16* WtAll  = (u16*)(ws + 3 * NEL + NEL);
  float* SA   = ws + 3 * NEL + NEL + 524288;  // NSC*2048 each
  float* SB   = SA + NSC * 2048;
  float* CY   = SB + NSC * 2048;
  float* KVT  = Abuf;
  u16* Ptb    = (u16*)Gbuf;

  cvt_bf16<<<(int)(NEL / 4 / 256), 256, 0, stream>>>(q, qbf);
  wtrans<<<dim3(16, 16, 4), 256, 0, stream>>>(Wa, Wb, Wg, Wo, WtAll);

  // fused q @ {Wa|Wb|Wg}: N = 1536, sigmoid on groups 0 and 2
  gemm_bt<<<dim3(12, 64), 256, 0, stream>>>(qbf, WtAll, ba, bb, bg,
                                            Abuf, Bbuf, Gbuf, 0b101);

  scan_part<<<dim3(NSC, 8), 256, 0, stream>>>(Abuf, Bbuf, SA, SB);
  scan_carry<<<8, 256, 0, stream>>>(SA, SB, CY);
  scan_apply<<<dim3(NSC, 8), 256, 0, stream>>>(Abuf, Bbuf, Gbuf, CY, hgbf);

  // m_out = (h*g) @ Wo + bo -> out
  gemm_bt<<<dim3(4, 64), 256, 0, stream>>>(hgbf, WtAll + 3 * DIM * DIM,
                                           bo, bo, bo, out, out, out, 0);

  ret_kv<<<dim3(BHN, NC), 256, 0, stream>>>(k, v, KVT);
  ret_scan<<<(BHN * 4096) / 256, 256, 0, stream>>>(KVT, Ptb);
  ret_out<<<dim3(BHN, NC), 256, 0, stream>>>(qbf, k, v, Ptb, out);
}